// Round 5
// baseline (100.862 us; speedup 1.0000x reference)
//
#include <hip/hip_runtime.h>

// ante[e, i*3+j] = exp(-2*(x1 - c_i)^2) * exp(-2*(x2 - c_j)^2)
// x1 = feat[dst][0] - feat[src][0], x2 = feat[dst][1] - feat[src][1]
// c = {-1, 0, +1}, 1/(2*sigma^2) = 2.0
//
// R5: shrink the gather footprint. R4 showed occupancy is NOT the limiter
// (4->8 blocks/CU changed nothing); hypothesis is gather-side L2 misses:
// the 230MB write stream evicts feat (3.2MB, only 2 rows per 64B line) from
// the 4MB per-XCD L2s. Prepass packs coords -> 800KB float2 array in d_ws:
// 4x fewer lines, 8 nodes per 64B line, more eviction-resistant.
// Store path unchanged from R3/R4 (LDS transpose, contiguous b128 stores).

#define TPB 256

typedef float  f2 __attribute__((ext_vector_type(2)));
typedef float  f4 __attribute__((ext_vector_type(4)));
typedef int    i2 __attribute__((ext_vector_type(2)));

__global__ __launch_bounds__(TPB) void pack_coords(
    const float* __restrict__ feat, f2* __restrict__ packed, int n)
{
    const int i = blockIdx.x * TPB + threadIdx.x;
    if (i < n)
        packed[i] = *reinterpret_cast<const f2*>(feat + (size_t)i * 8);
}

__global__ __launch_bounds__(TPB, 8) void ante_kernel(
    const f2*  __restrict__ coords,   // packed (stride 1) or feat (stride 4)
    int        cstride,               // in f2 units
    const int* __restrict__ esrc,
    const int* __restrict__ edst,
    float*     __restrict__ out,
    int e2,      // number of 2-edge groups
    int nf4)     // total output float4 count
{
    __shared__ float lds[TPB * 18];   // 18 KB/block -> 8 blocks/CU
    const int tid = threadIdx.x;
    const int t   = blockIdx.x * TPB + tid;

    if (t < e2) {
        const i2 s2 = __builtin_nontemporal_load(reinterpret_cast<const i2*>(esrc) + t);
        const i2 d2 = __builtin_nontemporal_load(reinterpret_cast<const i2*>(edst) + t);

        // Issue all 4 gathers before any arithmetic (maximize MLP).
        const f2 fs0 = coords[(size_t)s2.x * cstride];
        const f2 fd0 = coords[(size_t)d2.x * cstride];
        const f2 fs1 = coords[(size_t)s2.y * cstride];
        const f2 fd1 = coords[(size_t)d2.y * cstride];

        float res[18];
#pragma unroll
        for (int q = 0; q < 2; ++q) {
            const float x1 = (q == 0) ? (fd0.x - fs0.x) : (fd1.x - fs1.x);
            const float x2 = (q == 0) ? (fd0.y - fs0.y) : (fd1.y - fs1.y);

            float m1[3], m2[3];
            {
                const float a = x1 + 1.0f, c = x1 - 1.0f;
                m1[0] = __expf(-2.0f * a * a);
                m1[1] = __expf(-2.0f * x1 * x1);
                m1[2] = __expf(-2.0f * c * c);
            }
            {
                const float a = x2 + 1.0f, c = x2 - 1.0f;
                m2[0] = __expf(-2.0f * a * a);
                m2[1] = __expf(-2.0f * x2 * x2);
                m2[2] = __expf(-2.0f * c * c);
            }
#pragma unroll
            for (int i = 0; i < 3; ++i)
#pragma unroll
                for (int j = 0; j < 3; ++j)
                    res[q * 9 + i * 3 + j] = m1[i] * m2[j];
        }

        // 9 x ds_write_b64, dword base 18*tid (8B aligned), bank-floor pattern.
        f2* my2 = reinterpret_cast<f2*>(lds) + tid * 9;
#pragma unroll
        for (int k = 0; k < 9; ++k) {
            f2 v; v.x = res[2 * k]; v.y = res[2 * k + 1];
            my2[k] = v;
        }
    }
    __syncthreads();

    // Store phase: float4 slot f = k*TPB+tid is both LDS f4 index and the
    // output f4 index within the block's span (1152 f4 per block).
    const size_t blk_f4 = (size_t)blockIdx.x * (TPB * 9 / 2);
    f4* out4 = reinterpret_cast<f4*>(out);
    const f4* lds4 = reinterpret_cast<const f4*>(lds);

#pragma unroll
    for (int k = 0; k < 5; ++k) {
        const int f = k * TPB + tid;
        if (f < TPB * 9 / 2) {
            const size_t g = blk_f4 + (size_t)f;
            if (g < (size_t)nf4)
                __builtin_nontemporal_store(lds4[f], out4 + g);
        }
    }
}

extern "C" void kernel_launch(void* const* d_in, const int* in_sizes, int n_in,
                              void* d_out, int out_size, void* d_ws, size_t ws_size,
                              hipStream_t stream) {
    const float* feat = (const float*)d_in[0];
    const int*   esrc = (const int*)d_in[1];
    const int*   edst = (const int*)d_in[2];
    // d_in[3] = etypes, unused by the reference output
    float* out = (float*)d_out;

    const int N   = in_sizes[0] / 8;     // 100,000 nodes (D_FEAT = 8)
    const int E   = in_sizes[1];         // 6,400,000
    const int e2  = E / 2;               // 2-edge groups
    const int nf4 = out_size / 4;        // output float4 count

    const f2* coords;
    int cstride;
    if (ws_size >= (size_t)N * sizeof(float) * 2) {
        f2* packed = (f2*)d_ws;
        pack_coords<<<(N + TPB - 1) / TPB, TPB, 0, stream>>>(feat, packed, N);
        coords  = packed;
        cstride = 1;
    } else {
        coords  = reinterpret_cast<const f2*>(feat);
        cstride = 4;   // feat row = 8 floats = 4 f2
    }

    const int grid = (e2 + TPB - 1) / TPB;
    ante_kernel<<<grid, TPB, 0, stream>>>(coords, cstride, esrc, edst, out, e2, nf4);
}